// Round 16
// baseline (212.398 us; speedup 1.0000x reference)
//
#include <hip/hip_runtime.h>
#include <cstdint>
#include <cstddef>

// ---------------------------------------------------------------------------
// LSTM cell, B=8192, D=H=512, fp32 in/out.
// pre = [x|h] @ Wstack^T + bias ; gates -> c_t, h_t fused in GEMM epilogue.
// Round 19: champion + full c_prev hoist. All 16 c_prev loads (64 B/thread)
// issue BEFORE the K-loop, pinned via empty asm so the compiler cannot sink
// them back to their epilogue uses (r8 showed it sinks otherwise). Their
// HBM latency + the 16 MB stream now overlap the ~40us K-loop (which runs
// at only ~0.4 TB/s demand) instead of compressing into the epilogue's
// barrier windows. Same addresses/values -> bit-identical output; +16 VGPR
// (64->~80) is free at the grid-limited 2 blocks/CU.
// Session ledger: seven K-loop/shape rewrites negative (8-phase x2, 4blk/CU,
// fp32-direct, reg-direct, dbuf-drain, counted-vmcnt, 32x32-MFMA); r17's
// float4-store epilogue refuted (write-stream scatter -> RFO+amplification).
// Wins: epilogue grafts, pack width, (this) hoist class. GEMM FETCH ~33MB ==
// compulsory. Remaining gap = 2-barrier stage-drain stall (m233); verified
// escape (m201 8-phase) did not reproduce (guide's open m232 quadrant).
// ---------------------------------------------------------------------------

typedef __attribute__((ext_vector_type(8))) short short8;   // 8 bf16 = 4 VGPRs
typedef __attribute__((ext_vector_type(4))) float floatx4;  // MFMA acc

#define AS1(p) ((const __attribute__((address_space(1))) void*)(p))
#define AS3(p) ((__attribute__((address_space(3))) void*)(p))

__device__ __forceinline__ unsigned short f2bf(float f) {
  union { float f; unsigned u; } v; v.f = f;
  unsigned u = v.u;
  return (unsigned short)((u + 0x7fffu + ((u >> 16) & 1u)) >> 16);  // RNE
}

// --------------------------- pack everything -------------------------------
// A[b][k] = k<512 ? x[b][k] : h[b][k-512]                  (8192x1024 bf16)
// B[n][k], n = hh*4 + g (h-interleaved gates f,i,g,o), k<512 -> Wx else Wh;
// bias[n] = bx+bh written by the k==0 thread.  8 elems/thread.
struct PackArgs {
  const float* x; const float* h;
  const float* wx[4]; const float* wh[4];
  const float* bx[4]; const float* bh[4];
  unsigned short* A; unsigned short* B; float* bias;
};

__global__ __launch_bounds__(256) void pack_all_kernel(PackArgs P) {
  const int d = blockIdx.x;
  int blk;
  if (d < 4096) {                         // A region: XCD-aligned remap (neutral)
    int p = (d & 7) + ((d >> 10) << 3);   // panel 0..31
    int i = (d >> 3) & 127;
    blk = p * 128 + i;
  } else {
    blk = d;                              // B region unchanged
  }
  const int gid = blk * 256 + threadIdx.x;
  const float* src;
  unsigned short* dst;
  if (gid < 1048576) {                    // ---- A: 8192 rows x 128 chunks ----
    int b = gid >> 7, k = (gid & 127) * 8;
    src = (k < 512) ? (P.x + b * 512 + k) : (P.h + b * 512 + (k - 512));
    dst = P.A + ((size_t)b << 10) + k;
  } else {                                // ---- B: 2048 rows x 128 chunks ----
    int g2 = gid - 1048576;
    int n = g2 >> 7, k = (g2 & 127) * 8;
    int g = n & 3, hh = n >> 2;           // h-interleaved layout
    src = (k < 512) ? (P.wx[g] + hh * 512 + k) : (P.wh[g] + hh * 512 + (k - 512));
    dst = P.B + ((size_t)n << 10) + k;
    if (k == 0) P.bias[n] = P.bx[g][hh] + P.bh[g][hh];
  }
  float4 v0 = ((const float4*)src)[0];
  float4 v1 = ((const float4*)src)[1];
  union { unsigned short us[8]; short8 s; } o;
  o.us[0] = f2bf(v0.x); o.us[1] = f2bf(v0.y);
  o.us[2] = f2bf(v0.z); o.us[3] = f2bf(v0.w);
  o.us[4] = f2bf(v1.x); o.us[5] = f2bf(v1.y);
  o.us[6] = f2bf(v1.z); o.us[7] = f2bf(v1.w);
  *(short8*)dst = o.s;
}

// --------------------------- fused GEMM + LSTM epilogue --------------------
// Grid (32,16): tile = 256 batch x 128 cols (32 hidden x 4 gates). K=1024,
// BK=64. 512 threads = 8 waves; wave tile 64x64 (4x4 frags of 16x16x32).
// LDS: As 32KB @ [0,32768), Bs 16KB @ [32768,49152); epilogue overlays As.
__global__ __launch_bounds__(512, 4)
void lstm_gemm_kernel(const unsigned short* __restrict__ A,   // [8192][1024]
                      const unsigned short* __restrict__ B,   // [2048][1024]
                      const float* __restrict__ bias,         // [2048]
                      const float* __restrict__ c_prev,       // [8192][512]
                      float* __restrict__ h_out,              // [8192][512]
                      float* __restrict__ c_out) {            // [8192][512]
  __shared__ __align__(16) char smem[49152];
  __shared__ __align__(16) float biasS[128];

  const int tid  = threadIdx.x;
  const int lane = tid & 63;
  const int w    = tid >> 6;        // wave 0..7
  const int quad = lane >> 4;
  const int colA = lane & 15;
  const int m0   = blockIdx.x * 256;
  const int n0   = blockIdx.y * 128;    // = 4*h0
  const int h0   = blockIdx.y * 32;

  if (tid < 128) biasS[tid] = bias[n0 + tid];   // contiguous (h-interleave)

  // staging: thread covers tile-row r = j*64 + (tid>>3), 16B chunk (tid&7);
  // global chunk XOR-swizzled by row&7 so ds_read_b128 frags are conflict-free
  const int srow = tid >> 3;        // 0..63
  const int cl   = tid & 7;
  const int cg   = cl ^ (srow & 7);

  floatx4 acc[4][4];
#pragma unroll
  for (int i = 0; i < 4; ++i)
#pragma unroll
    for (int j = 0; j < 4; ++j) acc[i][j] = (floatx4){0.f, 0.f, 0.f, 0.f};

  const int wm = (w >> 1) * 64;     // wave M offset in tile (0,64,128,192)
  const int wn = (w & 1) * 64;      // wave N offset (0 or 64)

  // ---- c_prev fully hoisted: issue all 16 loads before the K-loop ----
  // (64 B/thread; latency + bandwidth overlap the K-loop, not the epilogue)
  float cp[4][4];
#pragma unroll
  for (int rd = 0; rd < 4; ++rd)
#pragma unroll
    for (int j = 0; j < 4; ++j) {
      int idx  = j * 512 + tid;     // 0..2047
      int mloc = idx >> 5;
      int hh   = idx & 31;
      cp[rd][j] = c_prev[(m0 + rd * 64 + mloc) * 512 + h0 + hh];
    }
  // pin: stop the compiler sinking these loads to their epilogue uses (r8)
#pragma unroll
  for (int rd = 0; rd < 4; ++rd)
#pragma unroll
    for (int j = 0; j < 4; ++j)
      asm volatile("" : "+v"(cp[rd][j]));

  const char* Ag = (const char*)A;
  const char* Bg = (const char*)B;

  for (int kt = 0; kt < 16; ++kt) {
    __syncthreads();                // prior LDS reads done
    const int kb = kt * 128;        // byte offset into 2048-B rows
#pragma unroll
    for (int j = 0; j < 4; ++j) {   // A: 256 rows
      int r = j * 64 + srow;        // tile row 0..255 (r&7 == srow&7)
      __builtin_amdgcn_global_load_lds(
          AS1(Ag + (size_t)(m0 + r) * 2048 + kb + cg * 16),
          AS3(smem + r * 128 + cl * 16), 16, 0, 0);
    }
#pragma unroll
    for (int j = 0; j < 2; ++j) {   // B: 128 rows (h-interleaved)
      int r = j * 64 + srow;        // tile row 0..127
      __builtin_amdgcn_global_load_lds(
          AS1(Bg + (size_t)(n0 + r) * 2048 + kb + cg * 16),
          AS3(smem + 32768 + r * 128 + cl * 16), 16, 0, 0);
    }
    __syncthreads();                // drains vmcnt(0)

#pragma unroll
    for (int kk = 0; kk < 2; ++kk) {
      const int off = ((kk * 4 + quad) ^ (colA & 7)) * 16;
      short8 af[4], bfr[4];
#pragma unroll
      for (int mi = 0; mi < 4; ++mi)
        af[mi] = *(const short8*)(smem + (wm + mi * 16 + colA) * 128 + off);
#pragma unroll
      for (int ni = 0; ni < 4; ++ni)
        bfr[ni] = *(const short8*)(smem + 32768 + (wn + ni * 16 + colA) * 128 + off);
#pragma unroll
      for (int mi = 0; mi < 4; ++mi)
#pragma unroll
        for (int ni = 0; ni < 4; ++ni)
          acc[mi][ni] = __builtin_amdgcn_mfma_f32_16x16x32_bf16(
              af[mi], bfr[ni], acc[mi][ni], 0, 0, 0);
    }
  }

  // ------------------- fused epilogue (4 rounds of 64 M-rows) --------------
  __syncthreads();
  float* ep = (float*)smem;         // [64][132] padded, overlays As
#pragma unroll
  for (int rd = 0; rd < 4; ++rd) {
    if ((w >> 1) == rd) {           // the 2 waves with wm == rd*64
      // C/D layout: row = quad*4 + rr, col = lane&15
#pragma unroll
      for (int mi = 0; mi < 4; ++mi)
#pragma unroll
        for (int ni = 0; ni < 4; ++ni) {
          int rr0 = mi * 16 + quad * 4;                 // 0..63
          int cc  = wn + ni * 16 + colA;                // 0..127
#pragma unroll
          for (int rr = 0; rr < 4; ++rr)
            ep[(rr0 + rr) * 132 + cc] = acc[mi][ni][rr];
        }
    }
    __syncthreads();
#pragma unroll
    for (int j = 0; j < 4; ++j) {
      int idx  = j * 512 + tid;     // 0..2047
      int mloc = idx >> 5;
      int hh   = idx & 31;
      // one aligned float4 = (f,i,g,o) pre-activations for this (m,h)
      float4 pre = *(const float4*)(ep + mloc * 132 + hh * 4);
      float4 bb  = *(const float4*)(biasS + hh * 4);
      float pf = pre.x + bb.x;
      float pi = pre.y + bb.y;
      float pg = pre.z + bb.z;
      float po = pre.w + bb.w;
      float fg = 1.f / (1.f + __expf(-pf));
      float ig = 1.f / (1.f + __expf(-pi));
      float gg = 1.f - 2.f / (1.f + __expf(2.f * pg));
      float og = 1.f / (1.f + __expf(-po));
      float cv = fg * cp[rd][j] + ig * gg;
      float th = 1.f - 2.f / (1.f + __expf(2.f * cv));
      int m  = m0 + rd * 64 + mloc;
      int hg = h0 + hh;
      h_out[m * 512 + hg] = og * th;
      c_out[m * 512 + hg] = cv;
    }
    __syncthreads();
  }
}

// ---------------------------------------------------------------------------
extern "C" void kernel_launch(void* const* d_in, const int* in_sizes, int n_in,
                              void* d_out, int out_size, void* d_ws, size_t ws_size,
                              hipStream_t stream) {
  // workspace: A_bf16 (16 MiB) | B_bf16 (4 MiB) | bias (8 KiB)
  char* ws = (char*)d_ws;
  unsigned short* Abf = (unsigned short*)ws;
  unsigned short* Bbf = (unsigned short*)(ws + (size_t)16777216);
  float* bias = (float*)(ws + (size_t)16777216 + 4194304);

  float* hout = (float*)d_out;
  float* cout = hout + (size_t)8192 * 512;

  PackArgs P;
  P.x = (const float*)d_in[0];
  P.h = (const float*)d_in[1];
  // gate order: 0=f, 1=i, 2=g(cell), 3=o
  P.wx[0] = (const float*)d_in[3];  P.bx[0] = (const float*)d_in[4];
  P.wh[0] = (const float*)d_in[5];  P.bh[0] = (const float*)d_in[6];
  P.wx[1] = (const float*)d_in[7];  P.bx[1] = (const float*)d_in[8];
  P.wh[1] = (const float*)d_in[9];  P.bh[1] = (const float*)d_in[10];
  P.wx[2] = (const float*)d_in[11]; P.bx[2] = (const float*)d_in[12];
  P.wh[2] = (const float*)d_in[13]; P.bh[2] = (const float*)d_in[14];
  P.wx[3] = (const float*)d_in[15]; P.bx[3] = (const float*)d_in[16];
  P.wh[3] = (const float*)d_in[17]; P.bh[3] = (const float*)d_in[18];
  P.A = Abf; P.B = Bbf; P.bias = bias;

  // A: 1048576 threads + B: 262144 threads = 5120 blocks of 256
  pack_all_kernel<<<5120, 256, 0, stream>>>(P);

  const float* c = (const float*)d_in[2];
  dim3 grid(32, 16);
  lstm_gemm_kernel<<<grid, 512, 0, stream>>>(Abf, Bbf, bias, c, hout, cout);
}

// Round 17
// 167.116 us; speedup vs baseline: 1.2710x; 1.2710x over previous
//
#include <hip/hip_runtime.h>
#include <cstdint>
#include <cstddef>

// ---------------------------------------------------------------------------
// LSTM cell, B=8192, D=H=512, fp32 in/out.
// pre = [x|h] @ Wstack^T + bias ; gates -> c_t, h_t fused in GEMM epilogue.
// Round 20 = FINAL: byte-exact champion (r18 form; GEMM 46.8-49.7us, totals
// 164.8-170.2 across four runs).
// r19's full c_prev hoist REGRESSED (GEMM 92-109us): asm-pinning 16 floats
// across the K-loop made the allocator SPILL to scratch (VGPR stayed 64;
// WRITE 33->105MB, FETCH 33->85MB = spill traffic on HBM). Per-round hoist
// (4 live values, short window) is the correct granularity -- kept here.
// r17's float4-store epilogue also refuted (write-stream scatter -> RFO).
// Session ledger: seven K-loop/shape rewrites negative (8-phase x2, 4blk/CU,
// fp32-direct, reg-direct, dbuf-drain, counted-vmcnt, 32x32-MFMA). Wins:
// h-interleaved float4-read epilogue + per-round c_prev hoist (+2.4us),
// pack 8-elem width (+2.5us). GEMM FETCH ~33MB == compulsory (r15).
// Remaining gap = 2-barrier stage-drain stall (m233); its verified escape
// (m201 8-phase) did not reproduce here (guide's open m232 quadrant).
// ---------------------------------------------------------------------------

typedef __attribute__((ext_vector_type(8))) short short8;   // 8 bf16 = 4 VGPRs
typedef __attribute__((ext_vector_type(4))) float floatx4;  // MFMA acc

#define AS1(p) ((const __attribute__((address_space(1))) void*)(p))
#define AS3(p) ((__attribute__((address_space(3))) void*)(p))

__device__ __forceinline__ unsigned short f2bf(float f) {
  union { float f; unsigned u; } v; v.f = f;
  unsigned u = v.u;
  return (unsigned short)((u + 0x7fffu + ((u >> 16) & 1u)) >> 16);  // RNE
}

// --------------------------- pack everything -------------------------------
// A[b][k] = k<512 ? x[b][k] : h[b][k-512]                  (8192x1024 bf16)
// B[n][k], n = hh*4 + g (h-interleaved gates f,i,g,o), k<512 -> Wx else Wh;
// bias[n] = bx+bh written by the k==0 thread.  8 elems/thread.
struct PackArgs {
  const float* x; const float* h;
  const float* wx[4]; const float* wh[4];
  const float* bx[4]; const float* bh[4];
  unsigned short* A; unsigned short* B; float* bias;
};

__global__ __launch_bounds__(256) void pack_all_kernel(PackArgs P) {
  const int d = blockIdx.x;
  int blk;
  if (d < 4096) {                         // A region: XCD-aligned remap (neutral)
    int p = (d & 7) + ((d >> 10) << 3);   // panel 0..31
    int i = (d >> 3) & 127;
    blk = p * 128 + i;
  } else {
    blk = d;                              // B region unchanged
  }
  const int gid = blk * 256 + threadIdx.x;
  const float* src;
  unsigned short* dst;
  if (gid < 1048576) {                    // ---- A: 8192 rows x 128 chunks ----
    int b = gid >> 7, k = (gid & 127) * 8;
    src = (k < 512) ? (P.x + b * 512 + k) : (P.h + b * 512 + (k - 512));
    dst = P.A + ((size_t)b << 10) + k;
  } else {                                // ---- B: 2048 rows x 128 chunks ----
    int g2 = gid - 1048576;
    int n = g2 >> 7, k = (g2 & 127) * 8;
    int g = n & 3, hh = n >> 2;           // h-interleaved layout
    src = (k < 512) ? (P.wx[g] + hh * 512 + k) : (P.wh[g] + hh * 512 + (k - 512));
    dst = P.B + ((size_t)n << 10) + k;
    if (k == 0) P.bias[n] = P.bx[g][hh] + P.bh[g][hh];
  }
  float4 v0 = ((const float4*)src)[0];
  float4 v1 = ((const float4*)src)[1];
  union { unsigned short us[8]; short8 s; } o;
  o.us[0] = f2bf(v0.x); o.us[1] = f2bf(v0.y);
  o.us[2] = f2bf(v0.z); o.us[3] = f2bf(v0.w);
  o.us[4] = f2bf(v1.x); o.us[5] = f2bf(v1.y);
  o.us[6] = f2bf(v1.z); o.us[7] = f2bf(v1.w);
  *(short8*)dst = o.s;
}

// --------------------------- fused GEMM + LSTM epilogue --------------------
// Grid (32,16): tile = 256 batch x 128 cols (32 hidden x 4 gates). K=1024,
// BK=64. 512 threads = 8 waves; wave tile 64x64 (4x4 frags of 16x16x32).
// LDS: As 32KB @ [0,32768), Bs 16KB @ [32768,49152); epilogue overlays As.
__global__ __launch_bounds__(512, 4)
void lstm_gemm_kernel(const unsigned short* __restrict__ A,   // [8192][1024]
                      const unsigned short* __restrict__ B,   // [2048][1024]
                      const float* __restrict__ bias,         // [2048]
                      const float* __restrict__ c_prev,       // [8192][512]
                      float* __restrict__ h_out,              // [8192][512]
                      float* __restrict__ c_out) {            // [8192][512]
  __shared__ __align__(16) char smem[49152];
  __shared__ __align__(16) float biasS[128];

  const int tid  = threadIdx.x;
  const int lane = tid & 63;
  const int w    = tid >> 6;        // wave 0..7
  const int quad = lane >> 4;
  const int colA = lane & 15;
  const int m0   = blockIdx.x * 256;
  const int n0   = blockIdx.y * 128;    // = 4*h0
  const int h0   = blockIdx.y * 32;

  if (tid < 128) biasS[tid] = bias[n0 + tid];   // contiguous (h-interleave)

  // staging: thread covers tile-row r = j*64 + (tid>>3), 16B chunk (tid&7);
  // global chunk XOR-swizzled by row&7 so ds_read_b128 frags are conflict-free
  const int srow = tid >> 3;        // 0..63
  const int cl   = tid & 7;
  const int cg   = cl ^ (srow & 7);

  floatx4 acc[4][4];
#pragma unroll
  for (int i = 0; i < 4; ++i)
#pragma unroll
    for (int j = 0; j < 4; ++j) acc[i][j] = (floatx4){0.f, 0.f, 0.f, 0.f};

  const int wm = (w >> 1) * 64;     // wave M offset in tile (0,64,128,192)
  const int wn = (w & 1) * 64;      // wave N offset (0 or 64)

  const char* Ag = (const char*)A;
  const char* Bg = (const char*)B;

  for (int kt = 0; kt < 16; ++kt) {
    __syncthreads();                // prior LDS reads done
    const int kb = kt * 128;        // byte offset into 2048-B rows
#pragma unroll
    for (int j = 0; j < 4; ++j) {   // A: 256 rows
      int r = j * 64 + srow;        // tile row 0..255 (r&7 == srow&7)
      __builtin_amdgcn_global_load_lds(
          AS1(Ag + (size_t)(m0 + r) * 2048 + kb + cg * 16),
          AS3(smem + r * 128 + cl * 16), 16, 0, 0);
    }
#pragma unroll
    for (int j = 0; j < 2; ++j) {   // B: 128 rows (h-interleaved)
      int r = j * 64 + srow;        // tile row 0..127
      __builtin_amdgcn_global_load_lds(
          AS1(Bg + (size_t)(n0 + r) * 2048 + kb + cg * 16),
          AS3(smem + 32768 + r * 128 + cl * 16), 16, 0, 0);
    }
    __syncthreads();                // drains vmcnt(0)

#pragma unroll
    for (int kk = 0; kk < 2; ++kk) {
      const int off = ((kk * 4 + quad) ^ (colA & 7)) * 16;
      short8 af[4], bfr[4];
#pragma unroll
      for (int mi = 0; mi < 4; ++mi)
        af[mi] = *(const short8*)(smem + (wm + mi * 16 + colA) * 128 + off);
#pragma unroll
      for (int ni = 0; ni < 4; ++ni)
        bfr[ni] = *(const short8*)(smem + 32768 + (wn + ni * 16 + colA) * 128 + off);
#pragma unroll
      for (int mi = 0; mi < 4; ++mi)
#pragma unroll
        for (int ni = 0; ni < 4; ++ni)
          acc[mi][ni] = __builtin_amdgcn_mfma_f32_16x16x32_bf16(
              af[mi], bfr[ni], acc[mi][ni], 0, 0, 0);
    }
  }

  // ------------------- fused epilogue (4 rounds of 64 M-rows) --------------
  __syncthreads();
  float* ep = (float*)smem;         // [64][132] padded, overlays As
#pragma unroll
  for (int rd = 0; rd < 4; ++rd) {
    // c_prev hoisted per-round: HBM latency hides under ep writes + barrier
    float cp[4];
#pragma unroll
    for (int j = 0; j < 4; ++j) {
      int idx  = j * 512 + tid;     // 0..2047
      int mloc = idx >> 5;
      int hh   = idx & 31;
      cp[j] = c_prev[(m0 + rd * 64 + mloc) * 512 + h0 + hh];
    }
    if ((w >> 1) == rd) {           // the 2 waves with wm == rd*64
      // C/D layout: row = quad*4 + rr, col = lane&15
#pragma unroll
      for (int mi = 0; mi < 4; ++mi)
#pragma unroll
        for (int ni = 0; ni < 4; ++ni) {
          int rr0 = mi * 16 + quad * 4;                 // 0..63
          int cc  = wn + ni * 16 + colA;                // 0..127
#pragma unroll
          for (int rr = 0; rr < 4; ++rr)
            ep[(rr0 + rr) * 132 + cc] = acc[mi][ni][rr];
        }
    }
    __syncthreads();
#pragma unroll
    for (int j = 0; j < 4; ++j) {
      int idx  = j * 512 + tid;     // 0..2047
      int mloc = idx >> 5;
      int hh   = idx & 31;
      // one aligned float4 = (f,i,g,o) pre-activations for this (m,h)
      float4 pre = *(const float4*)(ep + mloc * 132 + hh * 4);
      float4 bb  = *(const float4*)(biasS + hh * 4);
      float pf = pre.x + bb.x;
      float pi = pre.y + bb.y;
      float pg = pre.z + bb.z;
      float po = pre.w + bb.w;
      float fg = 1.f / (1.f + __expf(-pf));
      float ig = 1.f / (1.f + __expf(-pi));
      float gg = 1.f - 2.f / (1.f + __expf(2.f * pg));
      float og = 1.f / (1.f + __expf(-po));
      float cv = fg * cp[j] + ig * gg;
      float th = 1.f - 2.f / (1.f + __expf(2.f * cv));
      int m  = m0 + rd * 64 + mloc;
      int hg = h0 + hh;
      h_out[m * 512 + hg] = og * th;
      c_out[m * 512 + hg] = cv;
    }
    __syncthreads();
  }
}

// ---------------------------------------------------------------------------
extern "C" void kernel_launch(void* const* d_in, const int* in_sizes, int n_in,
                              void* d_out, int out_size, void* d_ws, size_t ws_size,
                              hipStream_t stream) {
  // workspace: A_bf16 (16 MiB) | B_bf16 (4 MiB) | bias (8 KiB)
  char* ws = (char*)d_ws;
  unsigned short* Abf = (unsigned short*)ws;
  unsigned short* Bbf = (unsigned short*)(ws + (size_t)16777216);
  float* bias = (float*)(ws + (size_t)16777216 + 4194304);

  float* hout = (float*)d_out;
  float* cout = hout + (size_t)8192 * 512;

  PackArgs P;
  P.x = (const float*)d_in[0];
  P.h = (const float*)d_in[1];
  // gate order: 0=f, 1=i, 2=g(cell), 3=o
  P.wx[0] = (const float*)d_in[3];  P.bx[0] = (const float*)d_in[4];
  P.wh[0] = (const float*)d_in[5];  P.bh[0] = (const float*)d_in[6];
  P.wx[1] = (const float*)d_in[7];  P.bx[1] = (const float*)d_in[8];
  P.wh[1] = (const float*)d_in[9];  P.bh[1] = (const float*)d_in[10];
  P.wx[2] = (const float*)d_in[11]; P.bx[2] = (const float*)d_in[12];
  P.wh[2] = (const float*)d_in[13]; P.bh[2] = (const float*)d_in[14];
  P.wx[3] = (const float*)d_in[15]; P.bx[3] = (const float*)d_in[16];
  P.wh[3] = (const float*)d_in[17]; P.bh[3] = (const float*)d_in[18];
  P.A = Abf; P.B = Bbf; P.bias = bias;

  // A: 1048576 threads + B: 262144 threads = 5120 blocks of 256
  pack_all_kernel<<<5120, 256, 0, stream>>>(P);

  const float* c = (const float*)d_in[2];
  dim3 grid(32, 16);
  lstm_gemm_kernel<<<grid, 512, 0, stream>>>(Abf, Bbf, bias, c, hout, cout);
}

// Round 18
// 165.102 us; speedup vs baseline: 1.2865x; 1.0122x over previous
//
#include <hip/hip_runtime.h>
#include <cstdint>
#include <cstddef>

// ---------------------------------------------------------------------------
// LSTM cell, B=8192, D=H=512, fp32 in/out.
// pre = [x|h] @ Wstack^T + bias ; gates -> c_t, h_t fused in GEMM epilogue.
// FINAL (champion, 5x reproduced: total 167 +/- 3 us; GEMM 47-49 us at
// nominal clock). 256x128 tile, BK=64, 8 waves, 16x16x32 MFMA, XOR-swizzled
// global_load_lds staging (0 bank conflicts), h-interleaved float4-read
// LSTM epilogue with per-round c_prev hoist, pack v2 (8 elem/thread).
// r20's rocprof showed ~20% slower dispatches with IDENTICAL traffic
// counters -> container clock variance, not code.
// Ledger: 8-phase x2, dbuf-drain, counted-vmcnt, 4blk/CU, fp32-direct,
// reg-direct, 32x32-MFMA (+4.2M conflicts), float4-store epilogue (RFO),
// full c_prev hoist (scratch spill), XCD pack remap (neutral) -- all
// measured <= 0. Wins: epilogue grafts +2.4us, pack width +2.5us.
// GEMM FETCH ~33MB == compulsory. Remaining MfmaUtil gap = 2-barrier
// stage-drain plateau (m233); m201 escape did not reproduce (open m232).
// ---------------------------------------------------------------------------

typedef __attribute__((ext_vector_type(8))) short short8;   // 8 bf16 = 4 VGPRs
typedef __attribute__((ext_vector_type(4))) float floatx4;  // MFMA acc

#define AS1(p) ((const __attribute__((address_space(1))) void*)(p))
#define AS3(p) ((__attribute__((address_space(3))) void*)(p))

__device__ __forceinline__ unsigned short f2bf(float f) {
  union { float f; unsigned u; } v; v.f = f;
  unsigned u = v.u;
  return (unsigned short)((u + 0x7fffu + ((u >> 16) & 1u)) >> 16);  // RNE
}

// --------------------------- pack everything -------------------------------
// A[b][k] = k<512 ? x[b][k] : h[b][k-512]                  (8192x1024 bf16)
// B[n][k], n = hh*4 + g (h-interleaved gates f,i,g,o), k<512 -> Wx else Wh;
// bias[n] = bx+bh written by the k==0 thread.  8 elems/thread.
struct PackArgs {
  const float* x; const float* h;
  const float* wx[4]; const float* wh[4];
  const float* bx[4]; const float* bh[4];
  unsigned short* A; unsigned short* B; float* bias;
};

__global__ __launch_bounds__(256) void pack_all_kernel(PackArgs P) {
  const int d = blockIdx.x;
  int blk;
  if (d < 4096) {                         // A region: XCD-aligned remap (neutral)
    int p = (d & 7) + ((d >> 10) << 3);   // panel 0..31
    int i = (d >> 3) & 127;
    blk = p * 128 + i;
  } else {
    blk = d;                              // B region unchanged
  }
  const int gid = blk * 256 + threadIdx.x;
  const float* src;
  unsigned short* dst;
  if (gid < 1048576) {                    // ---- A: 8192 rows x 128 chunks ----
    int b = gid >> 7, k = (gid & 127) * 8;
    src = (k < 512) ? (P.x + b * 512 + k) : (P.h + b * 512 + (k - 512));
    dst = P.A + ((size_t)b << 10) + k;
  } else {                                // ---- B: 2048 rows x 128 chunks ----
    int g2 = gid - 1048576;
    int n = g2 >> 7, k = (g2 & 127) * 8;
    int g = n & 3, hh = n >> 2;           // h-interleaved layout
    src = (k < 512) ? (P.wx[g] + hh * 512 + k) : (P.wh[g] + hh * 512 + (k - 512));
    dst = P.B + ((size_t)n << 10) + k;
    if (k == 0) P.bias[n] = P.bx[g][hh] + P.bh[g][hh];
  }
  float4 v0 = ((const float4*)src)[0];
  float4 v1 = ((const float4*)src)[1];
  union { unsigned short us[8]; short8 s; } o;
  o.us[0] = f2bf(v0.x); o.us[1] = f2bf(v0.y);
  o.us[2] = f2bf(v0.z); o.us[3] = f2bf(v0.w);
  o.us[4] = f2bf(v1.x); o.us[5] = f2bf(v1.y);
  o.us[6] = f2bf(v1.z); o.us[7] = f2bf(v1.w);
  *(short8*)dst = o.s;
}

// --------------------------- fused GEMM + LSTM epilogue --------------------
// Grid (32,16): tile = 256 batch x 128 cols (32 hidden x 4 gates). K=1024,
// BK=64. 512 threads = 8 waves; wave tile 64x64 (4x4 frags of 16x16x32).
// LDS: As 32KB @ [0,32768), Bs 16KB @ [32768,49152); epilogue overlays As.
__global__ __launch_bounds__(512, 4)
void lstm_gemm_kernel(const unsigned short* __restrict__ A,   // [8192][1024]
                      const unsigned short* __restrict__ B,   // [2048][1024]
                      const float* __restrict__ bias,         // [2048]
                      const float* __restrict__ c_prev,       // [8192][512]
                      float* __restrict__ h_out,              // [8192][512]
                      float* __restrict__ c_out) {            // [8192][512]
  __shared__ __align__(16) char smem[49152];
  __shared__ __align__(16) float biasS[128];

  const int tid  = threadIdx.x;
  const int lane = tid & 63;
  const int w    = tid >> 6;        // wave 0..7
  const int quad = lane >> 4;
  const int colA = lane & 15;
  const int m0   = blockIdx.x * 256;
  const int n0   = blockIdx.y * 128;    // = 4*h0
  const int h0   = blockIdx.y * 32;

  if (tid < 128) biasS[tid] = bias[n0 + tid];   // contiguous (h-interleave)

  // staging: thread covers tile-row r = j*64 + (tid>>3), 16B chunk (tid&7);
  // global chunk XOR-swizzled by row&7 so ds_read_b128 frags are conflict-free
  const int srow = tid >> 3;        // 0..63
  const int cl   = tid & 7;
  const int cg   = cl ^ (srow & 7);

  floatx4 acc[4][4];
#pragma unroll
  for (int i = 0; i < 4; ++i)
#pragma unroll
    for (int j = 0; j < 4; ++j) acc[i][j] = (floatx4){0.f, 0.f, 0.f, 0.f};

  const int wm = (w >> 1) * 64;     // wave M offset in tile (0,64,128,192)
  const int wn = (w & 1) * 64;      // wave N offset (0 or 64)

  const char* Ag = (const char*)A;
  const char* Bg = (const char*)B;

  for (int kt = 0; kt < 16; ++kt) {
    __syncthreads();                // prior LDS reads done
    const int kb = kt * 128;        // byte offset into 2048-B rows
#pragma unroll
    for (int j = 0; j < 4; ++j) {   // A: 256 rows
      int r = j * 64 + srow;        // tile row 0..255 (r&7 == srow&7)
      __builtin_amdgcn_global_load_lds(
          AS1(Ag + (size_t)(m0 + r) * 2048 + kb + cg * 16),
          AS3(smem + r * 128 + cl * 16), 16, 0, 0);
    }
#pragma unroll
    for (int j = 0; j < 2; ++j) {   // B: 128 rows (h-interleaved)
      int r = j * 64 + srow;        // tile row 0..127
      __builtin_amdgcn_global_load_lds(
          AS1(Bg + (size_t)(n0 + r) * 2048 + kb + cg * 16),
          AS3(smem + 32768 + r * 128 + cl * 16), 16, 0, 0);
    }
    __syncthreads();                // drains vmcnt(0)

#pragma unroll
    for (int kk = 0; kk < 2; ++kk) {
      const int off = ((kk * 4 + quad) ^ (colA & 7)) * 16;
      short8 af[4], bfr[4];
#pragma unroll
      for (int mi = 0; mi < 4; ++mi)
        af[mi] = *(const short8*)(smem + (wm + mi * 16 + colA) * 128 + off);
#pragma unroll
      for (int ni = 0; ni < 4; ++ni)
        bfr[ni] = *(const short8*)(smem + 32768 + (wn + ni * 16 + colA) * 128 + off);
#pragma unroll
      for (int mi = 0; mi < 4; ++mi)
#pragma unroll
        for (int ni = 0; ni < 4; ++ni)
          acc[mi][ni] = __builtin_amdgcn_mfma_f32_16x16x32_bf16(
              af[mi], bfr[ni], acc[mi][ni], 0, 0, 0);
    }
  }

  // ------------------- fused epilogue (4 rounds of 64 M-rows) --------------
  __syncthreads();
  float* ep = (float*)smem;         // [64][132] padded, overlays As
#pragma unroll
  for (int rd = 0; rd < 4; ++rd) {
    // c_prev hoisted per-round: HBM latency hides under ep writes + barrier
    float cp[4];
#pragma unroll
    for (int j = 0; j < 4; ++j) {
      int idx  = j * 512 + tid;     // 0..2047
      int mloc = idx >> 5;
      int hh   = idx & 31;
      cp[j] = c_prev[(m0 + rd * 64 + mloc) * 512 + h0 + hh];
    }
    if ((w >> 1) == rd) {           // the 2 waves with wm == rd*64
      // C/D layout: row = quad*4 + rr, col = lane&15
#pragma unroll
      for (int mi = 0; mi < 4; ++mi)
#pragma unroll
        for (int ni = 0; ni < 4; ++ni) {
          int rr0 = mi * 16 + quad * 4;                 // 0..63
          int cc  = wn + ni * 16 + colA;                // 0..127
#pragma unroll
          for (int rr = 0; rr < 4; ++rr)
            ep[(rr0 + rr) * 132 + cc] = acc[mi][ni][rr];
        }
    }
    __syncthreads();
#pragma unroll
    for (int j = 0; j < 4; ++j) {
      int idx  = j * 512 + tid;     // 0..2047
      int mloc = idx >> 5;
      int hh   = idx & 31;
      // one aligned float4 = (f,i,g,o) pre-activations for this (m,h)
      float4 pre = *(const float4*)(ep + mloc * 132 + hh * 4);
      float4 bb  = *(const float4*)(biasS + hh * 4);
      float pf = pre.x + bb.x;
      float pi = pre.y + bb.y;
      float pg = pre.z + bb.z;
      float po = pre.w + bb.w;
      float fg = 1.f / (1.f + __expf(-pf));
      float ig = 1.f / (1.f + __expf(-pi));
      float gg = 1.f - 2.f / (1.f + __expf(2.f * pg));
      float og = 1.f / (1.f + __expf(-po));
      float cv = fg * cp[j] + ig * gg;
      float th = 1.f - 2.f / (1.f + __expf(2.f * cv));
      int m  = m0 + rd * 64 + mloc;
      int hg = h0 + hh;
      h_out[m * 512 + hg] = og * th;
      c_out[m * 512 + hg] = cv;
    }
    __syncthreads();
  }
}

// ---------------------------------------------------------------------------
extern "C" void kernel_launch(void* const* d_in, const int* in_sizes, int n_in,
                              void* d_out, int out_size, void* d_ws, size_t ws_size,
                              hipStream_t stream) {
  // workspace: A_bf16 (16 MiB) | B_bf16 (4 MiB) | bias (8 KiB)
  char* ws = (char*)d_ws;
  unsigned short* Abf = (unsigned short*)ws;
  unsigned short* Bbf = (unsigned short*)(ws + (size_t)16777216);
  float* bias = (float*)(ws + (size_t)16777216 + 4194304);

  float* hout = (float*)d_out;
  float* cout = hout + (size_t)8192 * 512;

  PackArgs P;
  P.x = (const float*)d_in[0];
  P.h = (const float*)d_in[1];
  // gate order: 0=f, 1=i, 2=g(cell), 3=o
  P.wx[0] = (const float*)d_in[3];  P.bx[0] = (const float*)d_in[4];
  P.wh[0] = (const float*)d_in[5];  P.bh[0] = (const float*)d_in[6];
  P.wx[1] = (const float*)d_in[7];  P.bx[1] = (const float*)d_in[8];
  P.wh[1] = (const float*)d_in[9];  P.bh[1] = (const float*)d_in[10];
  P.wx[2] = (const float*)d_in[11]; P.bx[2] = (const float*)d_in[12];
  P.wh[2] = (const float*)d_in[13]; P.bh[2] = (const float*)d_in[14];
  P.wx[3] = (const float*)d_in[15]; P.bx[3] = (const float*)d_in[16];
  P.wh[3] = (const float*)d_in[17]; P.bh[3] = (const float*)d_in[18];
  P.A = Abf; P.B = Bbf; P.bias = bias;

  // A: 1048576 threads + B: 262144 threads = 5120 blocks of 256
  pack_all_kernel<<<5120, 256, 0, stream>>>(P);

  const float* c = (const float*)d_in[2];
  dim3 grid(32, 16);
  lstm_gemm_kernel<<<grid, 512, 0, stream>>>(Abf, Bbf, bias, c, hout, cout);
}